// Round 9
// baseline (327.945 us; speedup 1.0000x reference)
//
#include <hip/hip_runtime.h>

#define TEMP 0.07f
#define NSLOT 132   // 8 row-side (q) + 124 col-side ((t-1)*4 + wave, t=1..31)

typedef __attribute__((ext_vector_type(4))) float f32x4;
typedef __attribute__((ext_vector_type(4))) int   i32x4;
typedef __attribute__((ext_vector_type(8))) int   i32x8;

// L2-normalize rows of X (fp32, N x 512) -> fp8 e4m3 (1 B/elem). One wave/row.
// Also zeroes the scalar output (replaces a hipMemsetAsync dispatch).
__global__ __launch_bounds__(256) void knorm(const float* __restrict__ X,
                                             unsigned char* __restrict__ Fq,
                                             float* __restrict__ out, int D) {
  if (blockIdx.x == 0 && threadIdx.x == 0) *out = 0.f;
  int row = blockIdx.x * 4 + (threadIdx.x >> 6);
  int lane = threadIdx.x & 63;
  const float4* xr = (const float4*)(X + (size_t)row * D);
  float4 a = xr[lane];
  float4 b = xr[lane + 64];
  float ss = a.x*a.x + a.y*a.y + a.z*a.z + a.w*a.w
           + b.x*b.x + b.y*b.y + b.z*b.z + b.w*b.w;
  #pragma unroll
  for (int off = 1; off < 64; off <<= 1) ss += __shfl_xor(ss, off, 64);
  float r = rsqrtf(ss);
  int lo = 0, hi = 0;
  lo = __builtin_amdgcn_cvt_pk_fp8_f32(a.x*r, a.y*r, lo, false);
  lo = __builtin_amdgcn_cvt_pk_fp8_f32(a.z*r, a.w*r, lo, true);
  hi = __builtin_amdgcn_cvt_pk_fp8_f32(b.x*r, b.y*r, hi, false);
  hi = __builtin_amdgcn_cvt_pk_fp8_f32(b.z*r, b.w*r, hi, true);
  unsigned char* op = Fq + (size_t)row * D;
  *(int*)(op + lane * 4)       = lo;
  *(int*)(op + 256 + lane * 4) = hi;
}

// Symmetric SupCon GEMM — BARRIER-FREE, LDS-FREE direct-gather version.
// Fq (4 MB) is XCD-L2-resident: staging it through LDS (R2-R8) only added
// barriers that phase-locked the waves. Here each wave gathers B fragments
// straight from global (L1/L2-hot; 4 waves/block share the same cols) and
// runs MFMA from registers. No __syncthreads / s_barrier in the loop ->
// 8 free-running waves/CU (512 blocks x 4 waves, VGPR<=256) hide latency.
// Enumeration (R8-validated): block (I,q), q in [0,8): A = rows of tile I
// (64 VGPR, 4 waves x 32 rows); walks J=(I+t)%64 for t=4q+1..4q+4. All
// unordered pairs once; t=32 computed by both partners, row-side only.
// Diagonal t=0 excluded; added analytically in kfinal (sim_ii = 1/T exact).
// Partials psum/pmask[slot][row]: row-side slot=q (0..7); col-side
// slot=8+(t-1)*4+wave (8..131) -- per-WAVE slots kill the cross-wave
// reduce (and its barriers). Every slot fully covered -> no memset.
__global__ __launch_bounds__(256, 2)
void kmain(const unsigned char* __restrict__ F, const int* __restrict__ tgt,
           float* __restrict__ psum, float* __restrict__ pmask, int N, int D) {
  const int tid  = threadIdx.x;
  const int lane = tid & 63;
  const int wave = tid >> 6;          // 0..3
  const int quad = lane >> 4;
  const int l15  = lane & 15;

  const int I = (int)blockIdx.x >> 3;
  const int q = (int)blockIdx.x & 7;  // 0..7
  const int rowbase = I * 128;

  // ---- A fragments: 2 mi x 4 ksteps x 32 fp8 (wave w -> rows +32w) ----
  i32x8 af[2][4];
  #pragma unroll
  for (int mi = 0; mi < 2; ++mi) {
    const unsigned char* rp = F + (size_t)(rowbase + wave*32 + mi*16 + l15) * 512 + quad*32;
    #pragma unroll
    for (int ks = 0; ks < 4; ++ks) {
      i32x4 lo = *(const i32x4*)(rp + ks*128);
      i32x4 hi = *(const i32x4*)(rp + ks*128 + 16);
      af[mi][ks] = __builtin_shufflevector(lo, hi, 0,1,2,3,4,5,6,7);
    }
  }

  int trow[2][4];
  #pragma unroll
  for (int mi = 0; mi < 2; ++mi)
    #pragma unroll
    for (int r = 0; r < 4; ++r)
      trow[mi][r] = tgt[rowbase + wave*32 + mi*16 + quad*4 + r];

  float se[2][4], ms[2][4];
  #pragma unroll
  for (int mi = 0; mi < 2; ++mi)
    #pragma unroll
    for (int r = 0; r < 4; ++r) { se[mi][r] = 0.f; ms[mi][r] = 0.f; }

  const float C1 = (1.0f / TEMP) * 1.4426950408889634f;
  const float C0 = -C1;

  for (int c = 0; c < 4; ++c) {
    const int t = 4*q + 1 + c;
    const int J = (I + t) & 63;
    const bool lc = (t != 32);               // t=32: row-side only
    const unsigned char* Bt = F + (size_t)J * 128 * 512;

    f32x4 ce[2], cm[2];                      // per-half col accumulators
    #pragma unroll
    for (int h = 0; h < 2; ++h) { ce[h] = (f32x4){0,0,0,0}; cm[h] = (f32x4){0,0,0,0}; }

    #pragma unroll
    for (int h = 0; h < 2; ++h) {
      f32x4 acc[2][4];
      #pragma unroll
      for (int mi = 0; mi < 2; ++mi)
        #pragma unroll
        for (int ni = 0; ni < 4; ++ni)
          acc[mi][ni] = (f32x4){0.f, 0.f, 0.f, 0.f};

      // B fragment gather: lane (quad,l15) reads row h*64+ni*16+l15,
      // bytes ks*128 + quad*32 .. +32 (L1/L2-hot; shared across waves).
      const unsigned char* bp = Bt + (size_t)(h*64 + l15) * 512 + quad*32;
      #pragma unroll
      for (int ks = 0; ks < 4; ++ks) {
        #pragma unroll
        for (int ni = 0; ni < 4; ++ni) {
          const unsigned char* pp = bp + ni*(16*512) + ks*128;
          i32x4 lo = *(const i32x4*)pp;
          i32x4 hi = *(const i32x4*)(pp + 16);
          i32x8 bv = __builtin_shufflevector(lo, hi, 0,1,2,3,4,5,6,7);
          acc[0][ni] = __builtin_amdgcn_mfma_scale_f32_16x16x128_f8f6f4(
              af[0][ks], bv, acc[0][ni], 0, 0, 0, 0x7F7F7F7F, 0, 0x7F7F7F7F);
          acc[1][ni] = __builtin_amdgcn_mfma_scale_f32_16x16x128_f8f6f4(
              af[1][ks], bv, acc[1][ni], 0, 0, 0, 0x7F7F7F7F, 0, 0x7F7F7F7F);
        }
      }

      int tc[4];
      #pragma unroll
      for (int ni = 0; ni < 4; ++ni) tc[ni] = tgt[J*128 + h*64 + ni*16 + l15];
      #pragma unroll
      for (int mi = 0; mi < 2; ++mi)
        #pragma unroll
        for (int ni = 0; ni < 4; ++ni)
          #pragma unroll
          for (int r = 0; r < 4; ++r) {
            float v = acc[mi][ni][r];
            float e = __builtin_amdgcn_exp2f(fmaf(v, C1, C0));
            bool mt = (tc[ni] == trow[mi][r]);
            se[mi][r] += e; if (mt) ms[mi][r] += v;
            if (lc) { ce[h][ni] += e; if (mt) cm[h][ni] += v; }
          }
    }

    // col-side: reduce across quads in-wave, write per-wave slot
    if (lc) {
      const size_t cbase = (size_t)(8 + (t-1)*4 + wave) * N + J*128;
      #pragma unroll
      for (int h = 0; h < 2; ++h)
        #pragma unroll
        for (int ni = 0; ni < 4; ++ni) {
          float e = ce[h][ni], m = cm[h][ni];
          e += __shfl_xor(e, 16, 64); e += __shfl_xor(e, 32, 64);
          m += __shfl_xor(m, 16, 64); m += __shfl_xor(m, 32, 64);
          if (quad == 0) {
            psum [cbase + h*64 + ni*16 + l15] = e;
            pmask[cbase + h*64 + ni*16 + l15] = m;
          }
        }
    }
  }

  // ---- row-side partials -> slot q ----
  #pragma unroll
  for (int mi = 0; mi < 2; ++mi)
    #pragma unroll
    for (int r = 0; r < 4; ++r) {
      float sv = se[mi][r], mv = ms[mi][r];
      #pragma unroll
      for (int off = 1; off < 16; off <<= 1) {
        sv += __shfl_xor(sv, off, 64);
        mv += __shfl_xor(mv, off, 64);
      }
      if (l15 == 0) {
        int row = rowbase + wave*32 + mi*16 + quad*4 + r;
        psum [(size_t)q * N + row] = sv;
        pmask[(size_t)q * N + row] = mv;
      }
    }
}

// finalize: 32 blocks x 256 rows; per-block histogram, per-row term,
// wave reduce, one atomicAdd per block into pre-zeroed out.
// Diagonal analytic: s starts at exp(0)=1 (reference sim_ii=1/T exactly);
// m excludes the diagonal (matches mask - eye).
__global__ __launch_bounds__(256) void kfinal(
    const float* __restrict__ psum, const float* __restrict__ pmask,
    const int* __restrict__ tgt, float* __restrict__ out, int N, int nslot) {
  __shared__ int h[128];
  __shared__ float wsum[4];
  const int tid = threadIdx.x;
  if (tid < 128) h[tid] = 0;
  __syncthreads();
  for (int i = tid; i < N; i += 256) atomicAdd(&h[tgt[i] & 127], 1);
  __syncthreads();

  const int i = blockIdx.x * 256 + tid;
  float s = 1.f, m = 0.f;           // s starts at the diagonal term
  #pragma unroll 4
  for (int sp = 0; sp < nslot; ++sp) {
    s += psum[(size_t)sp * N + i];
    m += pmask[(size_t)sp * N + i];
  }
  const float invT = 1.0f / TEMP;
  float cnt = (float)(h[tgt[i] & 127] - 1);
  float term = m * invT / cnt - (logf(s) + invT);
  #pragma unroll
  for (int off = 1; off < 64; off <<= 1) term += __shfl_xor(term, off, 64);
  if ((tid & 63) == 0) wsum[tid >> 6] = term;
  __syncthreads();
  if (tid == 0)
    atomicAdd(out, -(wsum[0] + wsum[1] + wsum[2] + wsum[3]) / (float)N);
}

extern "C" void kernel_launch(void* const* d_in, const int* in_sizes, int n_in,
                              void* d_out, int out_size, void* d_ws, size_t ws_size,
                              hipStream_t stream) {
  const float* X  = (const float*)d_in[0];
  const int* tgt  = (const int*)d_in[1];
  float* out      = (float*)d_out;
  const int N = in_sizes[1];
  const int D = in_sizes[0] / N;

  char* w = (char*)d_ws;
  unsigned char* Fq = (unsigned char*)w;
  size_t off = (size_t)N * D;                           // fp8: 1 B/elem (4 MB)
  float* psum  = (float*)(w + off);
  size_t psz = (size_t)NSLOT * N * sizeof(float);       // 4.3 MB
  off += psz;
  float* pmask = (float*)(w + off);                     // total ws ~12.7 MB

  knorm<<<N / 4, 256, 0, stream>>>(X, Fq, out, D);
  kmain<<<512, 256, 0, stream>>>(Fq, tgt, psum, pmask, N, D);
  kfinal<<<N / 256, 256, 0, stream>>>(psum, pmask, tgt, out, N, NSLOT);
}

// Round 10
// 237.023 us; speedup vs baseline: 1.3836x; 1.3836x over previous
//
#include <hip/hip_runtime.h>

#define TEMP 0.07f
#define NSLOT 132   // 8 row-side (q) + 124 col-side ((t-1)*4 + wave, t=1..31)

typedef __attribute__((ext_vector_type(4))) float f32x4;
typedef __attribute__((ext_vector_type(4))) int   i32x4;
typedef __attribute__((ext_vector_type(8))) int   i32x8;

// L2-normalize rows of X (fp32, N x 512) -> fp8 e4m3 (1 B/elem). One wave/row.
// Also zeroes the scalar output (replaces a hipMemsetAsync dispatch).
__global__ __launch_bounds__(256) void knorm(const float* __restrict__ X,
                                             unsigned char* __restrict__ Fq,
                                             float* __restrict__ out, int D) {
  if (blockIdx.x == 0 && threadIdx.x == 0) *out = 0.f;
  int row = blockIdx.x * 4 + (threadIdx.x >> 6);
  int lane = threadIdx.x & 63;
  const float4* xr = (const float4*)(X + (size_t)row * D);
  float4 a = xr[lane];
  float4 b = xr[lane + 64];
  float ss = a.x*a.x + a.y*a.y + a.z*a.z + a.w*a.w
           + b.x*b.x + b.y*b.y + b.z*b.z + b.w*b.w;
  #pragma unroll
  for (int off = 1; off < 64; off <<= 1) ss += __shfl_xor(ss, off, 64);
  float r = rsqrtf(ss);
  int lo = 0, hi = 0;
  lo = __builtin_amdgcn_cvt_pk_fp8_f32(a.x*r, a.y*r, lo, false);
  lo = __builtin_amdgcn_cvt_pk_fp8_f32(a.z*r, a.w*r, lo, true);
  hi = __builtin_amdgcn_cvt_pk_fp8_f32(b.x*r, b.y*r, hi, false);
  hi = __builtin_amdgcn_cvt_pk_fp8_f32(b.z*r, b.w*r, hi, true);
  unsigned char* op = Fq + (size_t)row * D;
  *(int*)(op + lane * 4)       = lo;
  *(int*)(op + 256 + lane * 4) = hi;
}

// Symmetric SupCon GEMM = R2/R5 pipeline + R8 t-walk + R9 per-wave col slots.
// Block b = I*8+q (512 blocks, 2/CU, ZERO tail): A = rows of tile I
// (registers, 4 waves x 32 rows); walks tiles J=(I+t)%64 for t=4q+1..4q+4
// as 8 pipelined 64-col half-steps. All unordered pairs once (t=1..31 both
// sides; t=32 computed by both partners, row-side only; diagonal t=0
// analytic in kfinal: sim_ii = 1/T exactly).
// Pipeline (R2/R5-proven): 2 x 32 KB LDS dbuf (66 KB total -> 2 blocks/CU),
// depth-1 prefetch, counted s_waitcnt vmcnt(8) (in-order FIFO: col stores
// issued BEFORE the next STAGE keep the count conservative-correct), two
// raw s_barrier per step. __launch_bounds__(256,1): full VGPR budget, no
// spill (the ONLY config that has never spilled: R2/R5/R6 at 132-184 VGPR).
// Col side: per-tile ce/cm regs, quad-reduce (shfl 16/32) at tile end,
// quad0 writes per-WAVE slot 8+(t-1)*4+wave -> no cross-wave reduce, no
// extra barriers. Every (slot,row) written exactly once -> no memset.
__global__ __launch_bounds__(256, 1)
void kmain(const unsigned char* __restrict__ F, const int* __restrict__ tgt,
           float* __restrict__ psum, float* __restrict__ pmask, int N, int D) {
  __shared__ __align__(16) unsigned char Bs[2][64 * 512];  // 2 x 32 KB dbuf
  __shared__ int tgts[512];

  const int tid  = threadIdx.x;
  const int lane = tid & 63;
  const int wave = tid >> 6;          // 0..3
  const int quad = lane >> 4;
  const int l15  = lane & 15;

  const int I = (int)blockIdx.x >> 3;
  const int q = (int)blockIdx.x & 7;  // 0..7
  const int rowbase = I * 128;

  // ---- A fragments: 2 mi x 4 ksteps x 32 fp8 (wave w -> rows +32w) ----
  i32x8 af[2][4];
  #pragma unroll
  for (int mi = 0; mi < 2; ++mi) {
    const unsigned char* rp = F + (size_t)(rowbase + wave*32 + mi*16 + l15) * 512 + quad*32;
    #pragma unroll
    for (int ks = 0; ks < 4; ++ks) {
      i32x4 lo = *(const i32x4*)(rp + ks*128);
      i32x4 hi = *(const i32x4*)(rp + ks*128 + 16);
      af[mi][ks] = __builtin_shufflevector(lo, hi, 0,1,2,3,4,5,6,7);
    }
  }

  int trow[2][4];
  #pragma unroll
  for (int mi = 0; mi < 2; ++mi)
    #pragma unroll
    for (int r = 0; r < 4; ++r)
      trow[mi][r] = tgt[rowbase + wave*32 + mi*16 + quad*4 + r];

  // col targets for the 4 tiles (wrap mod 64) -> LDS
  #pragma unroll
  for (int it = 0; it < 2; ++it) {
    int i = tid + it * 256;
    int tile = (I + 4*q + 1 + (i >> 7)) & 63;
    tgts[i] = tgt[tile * 128 + (i & 127)];
  }

  float se[2][4], ms[2][4];
  #pragma unroll
  for (int mi = 0; mi < 2; ++mi)
    #pragma unroll
    for (int r = 0; r < 4; ++r) { se[mi][r] = 0.f; ms[mi][r] = 0.f; }
  f32x4 ce[2], cm[2];   // current-tile col accumulators [half]

  const float C1 = (1.0f / TEMP) * 1.4426950408889634f;
  const float C0 = -C1;
  const int sw0 = (quad * 2) ^ (l15 & 7);   // read-side swizzle (row&7 == l15&7)

  // stage half-step s: tile (I+4q+1+(s>>1))%64, half s&1 -> Bs[s&1].
  // 2048 16B slots / 256 thr = 8 loads; phys slot p holds logical p^(row&7).
  auto STAGE = [&](int s) {
    const int tile  = (I + 4*q + 1 + (s >> 1)) & 63;
    const int rbase = tile * 128 + (s & 1) * 64;
    unsigned char* db = &Bs[0][0] + (s & 1) * 32768;
    #pragma unroll
    for (int it = 0; it < 8; ++it) {
      const int L   = it * 256 + tid;
      const int row = L >> 5;
      const int ks  = (L & 31) ^ (row & 7);
      const unsigned char* gp = F + (size_t)(rbase + row) * 512 + ks * 16;
      __builtin_amdgcn_global_load_lds(
          (const __attribute__((address_space(1))) void*)gp,
          (__attribute__((address_space(3))) void*)(db + L * 16), 16, 0, 0);
    }
  };

  __syncthreads();            // drain A/trow/tgts loads -> clean vmcnt slate
  STAGE(0);                   // 8 loads in flight

  #pragma unroll
  for (int p = 0; p < 8; ++p) {
    if (p < 7) {
      STAGE(p + 1);           // 16 in flight
      asm volatile("s_waitcnt vmcnt(8)" ::: "memory");   // step p landed
    } else {
      asm volatile("s_waitcnt vmcnt(0)" ::: "memory");
    }
    __builtin_amdgcn_s_barrier();           // data p ready for all waves

    const int c = p >> 1, h = p & 1;
    const int t = 4*q + 1 + c;
    const bool lc = (t != 32);              // t=32: row-side only (uniform)
    if (h == 0) {
      ce[0] = (f32x4){0,0,0,0}; ce[1] = (f32x4){0,0,0,0};
      cm[0] = (f32x4){0,0,0,0}; cm[1] = (f32x4){0,0,0,0};
    }

    // ---- COMP on Bs[p&1] ----
    f32x4 acc[2][4];
    #pragma unroll
    for (int mi = 0; mi < 2; ++mi)
      #pragma unroll
      for (int ni = 0; ni < 4; ++ni)
        acc[mi][ni] = (f32x4){0.f, 0.f, 0.f, 0.f};

    const unsigned char* bb  = &Bs[0][0] + (p & 1) * 32768 + l15 * 512;
    const unsigned char* bp0 = bb + sw0 * 16;
    const unsigned char* bp1 = bb + (sw0 ^ 1) * 16;

    #pragma unroll
    for (int ks = 0; ks < 4; ++ks) {
      #pragma unroll
      for (int ni = 0; ni < 4; ++ni) {
        i32x4 b0 = *(const i32x4*)(bp0 + ni*8192 + ks*128);
        i32x4 b1 = *(const i32x4*)(bp1 + ni*8192 + ks*128);
        i32x8 bv = __builtin_shufflevector(b0, b1, 0,1,2,3,4,5,6,7);
        acc[0][ni] = __builtin_amdgcn_mfma_scale_f32_16x16x128_f8f6f4(
            af[0][ks], bv, acc[0][ni], 0, 0, 0, 0x7F7F7F7F, 0, 0x7F7F7F7F);
        acc[1][ni] = __builtin_amdgcn_mfma_scale_f32_16x16x128_f8f6f4(
            af[1][ks], bv, acc[1][ni], 0, 0, 0, 0x7F7F7F7F, 0, 0x7F7F7F7F);
      }
    }

    int tcg[4];
    #pragma unroll
    for (int ni = 0; ni < 4; ++ni) tcg[ni] = tgts[c*128 + h*64 + ni*16 + l15];
    #pragma unroll
    for (int mi = 0; mi < 2; ++mi)
      #pragma unroll
      for (int ni = 0; ni < 4; ++ni)
        #pragma unroll
        for (int r = 0; r < 4; ++r) {
          float v = acc[mi][ni][r];
          float e = __builtin_amdgcn_exp2f(fmaf(v, C1, C0));
          bool mt = (tcg[ni] == trow[mi][r]);
          se[mi][r] += e; if (mt) ms[mi][r] += v;
          if (lc) { ce[h][ni] += e; if (mt) cm[h][ni] += v; }
        }

    // tile complete at h==1: quad-reduce + per-wave col-slot write.
    // Stores issue BEFORE next step's STAGE -> older in the vmcnt FIFO ->
    // counted vmcnt(8) stays conservative-correct.
    if (h == 1 && lc) {
      const int J = (I + t) & 63;
      const size_t cbase = (size_t)(8 + (t-1)*4 + wave) * N + J*128;
      #pragma unroll
      for (int g = 0; g < 2; ++g)
        #pragma unroll
        for (int ni = 0; ni < 4; ++ni) {
          float e = ce[g][ni], m = cm[g][ni];
          e += __shfl_xor(e, 16, 64); e += __shfl_xor(e, 32, 64);
          m += __shfl_xor(m, 16, 64); m += __shfl_xor(m, 32, 64);
          if (quad == 0) {
            psum [cbase + g*64 + ni*16 + l15] = e;
            pmask[cbase + g*64 + ni*16 + l15] = m;
          }
        }
    }
    __builtin_amdgcn_s_barrier();           // buf p reads done before overwrite
  }

  // ---- row-side partials -> slot q ----
  #pragma unroll
  for (int mi = 0; mi < 2; ++mi)
    #pragma unroll
    for (int r = 0; r < 4; ++r) {
      float sv = se[mi][r], mv = ms[mi][r];
      #pragma unroll
      for (int off = 1; off < 16; off <<= 1) {
        sv += __shfl_xor(sv, off, 64);
        mv += __shfl_xor(mv, off, 64);
      }
      if (l15 == 0) {
        int row = rowbase + wave*32 + mi*16 + quad*4 + r;
        psum [(size_t)q * N + row] = sv;
        pmask[(size_t)q * N + row] = mv;
      }
    }
}

// finalize: 32 blocks x 256 rows; per-block histogram, per-row term,
// wave reduce, one atomicAdd per block into pre-zeroed out.
// Diagonal analytic: s starts at exp(0)=1 (reference sim_ii=1/T exactly);
// m excludes the diagonal (matches mask - eye).
__global__ __launch_bounds__(256) void kfinal(
    const float* __restrict__ psum, const float* __restrict__ pmask,
    const int* __restrict__ tgt, float* __restrict__ out, int N, int nslot) {
  __shared__ int h[128];
  __shared__ float wsum[4];
  const int tid = threadIdx.x;
  if (tid < 128) h[tid] = 0;
  __syncthreads();
  for (int i = tid; i < N; i += 256) atomicAdd(&h[tgt[i] & 127], 1);
  __syncthreads();

  const int i = blockIdx.x * 256 + tid;
  float s = 1.f, m = 0.f;           // s starts at the diagonal term
  #pragma unroll 4
  for (int sp = 0; sp < nslot; ++sp) {
    s += psum[(size_t)sp * N + i];
    m += pmask[(size_t)sp * N + i];
  }
  const float invT = 1.0f / TEMP;
  float cnt = (float)(h[tgt[i] & 127] - 1);
  float term = m * invT / cnt - (logf(s) + invT);
  #pragma unroll
  for (int off = 1; off < 64; off <<= 1) term += __shfl_xor(term, off, 64);
  if ((tid & 63) == 0) wsum[tid >> 6] = term;
  __syncthreads();
  if (tid == 0)
    atomicAdd(out, -(wsum[0] + wsum[1] + wsum[2] + wsum[3]) / (float)N);
}

extern "C" void kernel_launch(void* const* d_in, const int* in_sizes, int n_in,
                              void* d_out, int out_size, void* d_ws, size_t ws_size,
                              hipStream_t stream) {
  const float* X  = (const float*)d_in[0];
  const int* tgt  = (const int*)d_in[1];
  float* out      = (float*)d_out;
  const int N = in_sizes[1];
  const int D = in_sizes[0] / N;

  char* w = (char*)d_ws;
  unsigned char* Fq = (unsigned char*)w;
  size_t off = (size_t)N * D;                           // fp8: 1 B/elem (4 MB)
  float* psum  = (float*)(w + off);
  size_t psz = (size_t)NSLOT * N * sizeof(float);       // 4.3 MB
  off += psz;
  float* pmask = (float*)(w + off);                     // total ws ~12.7 MB

  knorm<<<N / 4, 256, 0, stream>>>(X, Fq, out, D);
  kmain<<<512, 256, 0, stream>>>(Fq, tgt, psum, pmask, N, D);
  kfinal<<<N / 256, 256, 0, stream>>>(psum, pmask, tgt, out, N, NSLOT);
}

// Round 11
// 116.054 us; speedup vs baseline: 2.8258x; 2.0424x over previous
//
#include <hip/hip_runtime.h>

#define BM 128
#define HBN 64
#define NSPLIT 8
#define TEMP 0.07f

typedef __attribute__((ext_vector_type(4))) float f32x4;
typedef __attribute__((ext_vector_type(4))) int   i32x4;
typedef __attribute__((ext_vector_type(8))) int   i32x8;

// L2-normalize rows of X (fp32, N x 512) -> fp8 e4m3 (1 B/elem). One wave/row.
// Also zeroes the scalar output (replaces the hipMemsetAsync dispatch).
__global__ __launch_bounds__(256) void knorm(const float* __restrict__ X,
                                             unsigned char* __restrict__ Fq,
                                             float* __restrict__ out, int D) {
  if (blockIdx.x == 0 && threadIdx.x == 0) *out = 0.f;
  int row = blockIdx.x * 4 + (threadIdx.x >> 6);
  int lane = threadIdx.x & 63;
  const float4* xr = (const float4*)(X + (size_t)row * D);
  float4 a = xr[lane];
  float4 b = xr[lane + 64];
  float ss = a.x*a.x + a.y*a.y + a.z*a.z + a.w*a.w
           + b.x*b.x + b.y*b.y + b.z*b.z + b.w*b.w;
  #pragma unroll
  for (int off = 1; off < 64; off <<= 1) ss += __shfl_xor(ss, off, 64);
  float r = rsqrtf(ss);
  int lo = 0, hi = 0;
  lo = __builtin_amdgcn_cvt_pk_fp8_f32(a.x*r, a.y*r, lo, false);
  lo = __builtin_amdgcn_cvt_pk_fp8_f32(a.z*r, a.w*r, lo, true);
  hi = __builtin_amdgcn_cvt_pk_fp8_f32(b.x*r, b.y*r, hi, false);
  hi = __builtin_amdgcn_cvt_pk_fp8_f32(b.z*r, b.w*r, hi, true);
  unsigned char* op = Fq + (size_t)row * D;
  *(int*)(op + lane * 4)       = lo;
  *(int*)(op + 256 + lane * 4) = hi;
}

// Fused sim-tile GEMM + exp/mask row accumulation (R2 structure, full work).
// MX-scaled MFMA (scales=1.0, bit-identical to e4m3, 2x rate). A resident
// in registers (32 rows x 512 B / wave). B: double-buffered 2x32KB LDS
// half-tiles, counted vmcnt(8) + raw barriers (R2-proven, 49.6 us).
// R11 changes (overlap, not work):
//  - DEFERRED FOLD (T15): step g's acc folds at the top of step g+1,
//    inside the barrier region where COMP(g+1)'s ds_reads/MFMAs issue ->
//    fold VALU fills the lgkm-wait and MFMA-issue bubbles.
//  - tgts staged to LDS in prologue -> no in-loop global loads; the vmcnt
//    FIFO holds exactly the 8 staging loads (counted wait is precise).
//  - s_setprio(1) around the MFMA cluster (fold gives role diversity).
// NO global stores / shfl chains inside the loop (R10 spill lesson).
__global__ __launch_bounds__(256, 1)
void kmain(const unsigned char* __restrict__ F, const int* __restrict__ tgt,
           float* __restrict__ psum, float* __restrict__ pmask, int N, int D) {
  __shared__ __align__(16) unsigned char Bs[2][HBN * 512];  // 2 x 32 KB
  __shared__ int tgts[1024];                                // split's col targets

  const int tid  = threadIdx.x;
  const int lane = tid & 63;
  const int wave = tid >> 6;
  const int quad = lane >> 4;
  const int l15  = lane & 15;

  const int rowblk   = blockIdx.x / NSPLIT;
  const int split    = blockIdx.x % NSPLIT;   // aligns with XCD round-robin -> L2 reuse
  const int rowbase  = rowblk * BM;
  const int colbase0 = split * (N / NSPLIT);
  const int NS       = N / NSPLIT;            // 1024
  const int GT       = NS / HBN;              // 16 half-tiles

  // ---- A fragments: 2 mi x 4 ksteps x 32 fp8 (i32x8) ----
  i32x8 af[2][4];
  #pragma unroll
  for (int mi = 0; mi < 2; ++mi) {
    const unsigned char* rp = F + (size_t)(rowbase + wave*32 + mi*16 + l15) * 512 + quad*32;
    #pragma unroll
    for (int ks = 0; ks < 4; ++ks) {
      i32x4 lo = *(const i32x4*)(rp + ks*128);
      i32x4 hi = *(const i32x4*)(rp + ks*128 + 16);
      af[mi][ks] = __builtin_shufflevector(lo, hi, 0,1,2,3,4,5,6,7);
    }
  }

  int trow[2][4];
  #pragma unroll
  for (int mi = 0; mi < 2; ++mi)
    #pragma unroll
    for (int r = 0; r < 4; ++r)
      trow[mi][r] = tgt[rowbase + wave*32 + mi*16 + quad*4 + r];

  // stage this split's targets into LDS (ds_read in the loop, keeps vmcnt clean)
  for (int i = tid; i < NS; i += 256) tgts[i] = tgt[colbase0 + i];

  float se[2][4], ms[2][4];
  #pragma unroll
  for (int mi = 0; mi < 2; ++mi)
    #pragma unroll
    for (int r = 0; r < 4; ++r) { se[mi][r] = 0.f; ms[mi][r] = 0.f; }

  const float C1 = (1.0f / TEMP) * 1.4426950408889634f;  // invT*log2(e)
  const float C0 = -C1;

  auto STAGE = [&](int g, int buf) {
    const int cb = colbase0 + g * HBN;
    #pragma unroll
    for (int it = 0; it < 8; ++it) {
      const int L   = it * 256 + tid;   // phys 16B-slot linear index (0..2047)
      const int row = L >> 5;           // 32 slots per row
      const int ks  = (L & 31) ^ (row & 7);
      const unsigned char* gp = F + (size_t)(cb + row) * 512 + ks * 16;
      __builtin_amdgcn_global_load_lds(
          (const __attribute__((address_space(1))) void*)gp,
          (__attribute__((address_space(3))) void*)(&Bs[buf][0] + L * 16), 16, 0, 0);
    }
  };

  // Per-lane read-side swizzle constant: row = ni*16 + l15 -> row&7 == l15&7.
  const int sw0 = (quad * 2) ^ (l15 & 7);

  // deferred-fold state: step g's accumulator + col targets, folded at g+1
  f32x4 accP[2][4];
  int   tcP[4];
  #pragma unroll
  for (int mi = 0; mi < 2; ++mi)
    #pragma unroll
    for (int ni = 0; ni < 4; ++ni)
      accP[mi][ni] = (f32x4){0.f, 0.f, 0.f, 0.f};
  #pragma unroll
  for (int ni = 0; ni < 4; ++ni) tcP[ni] = trow[0][0];   // fold of zeros: harmless

  // full drain: retires af/trow/tgts staging so NO compiler waits land in the loop
  __syncthreads();

  STAGE(0, 0);                               // prologue prefetch (8 in flight)

  for (int g = 0; g < GT; ++g) {
    if (g + 1 < GT) {
      STAGE(g + 1, (g + 1) & 1);             // outstanding <= 16
      asm volatile("s_waitcnt vmcnt(8)" ::: "memory");   // half g landed; next 8 in flight
    } else {
      asm volatile("s_waitcnt vmcnt(0)" ::: "memory");   // last half: full drain
    }
    __builtin_amdgcn_s_barrier();            // all waves see Bs[g&1] staged

    // ---- deferred fold of step g-1 (VALU; overlaps ds_read/MFMA below) ----
    #pragma unroll
    for (int mi = 0; mi < 2; ++mi)
      #pragma unroll
      for (int ni = 0; ni < 4; ++ni)
        #pragma unroll
        for (int r = 0; r < 4; ++r) {
          float v = accP[mi][ni][r];
          se[mi][r] += __builtin_amdgcn_exp2f(fmaf(v, C1, C0));
          if (tcP[ni] == trow[mi][r]) ms[mi][r] += v;
        }

    f32x4 acc[2][4];
    #pragma unroll
    for (int mi = 0; mi < 2; ++mi)
      #pragma unroll
      for (int ni = 0; ni < 4; ++ni)
        acc[mi][ni] = (f32x4){0.f, 0.f, 0.f, 0.f};

    const unsigned char* bb  = &Bs[0][0] + (g & 1) * (HBN * 512) + l15 * 512;
    const unsigned char* bp0 = bb + sw0 * 16;
    const unsigned char* bp1 = bb + (sw0 ^ 1) * 16;

    __builtin_amdgcn_s_setprio(1);
    #pragma unroll
    for (int ks = 0; ks < 4; ++ks) {
      #pragma unroll
      for (int ni = 0; ni < 4; ++ni) {
        i32x4 b0 = *(const i32x4*)(bp0 + ni*8192 + ks*128);
        i32x4 b1 = *(const i32x4*)(bp1 + ni*8192 + ks*128);
        i32x8 b = __builtin_shufflevector(b0, b1, 0,1,2,3,4,5,6,7);
        acc[0][ni] = __builtin_amdgcn_mfma_scale_f32_16x16x128_f8f6f4(
            af[0][ks], b, acc[0][ni], 0, 0, 0, 0x7F7F7F7F, 0, 0x7F7F7F7F);
        acc[1][ni] = __builtin_amdgcn_mfma_scale_f32_16x16x128_f8f6f4(
            af[1][ks], b, acc[1][ni], 0, 0, 0, 0x7F7F7F7F, 0, 0x7F7F7F7F);
      }
    }
    __builtin_amdgcn_s_setprio(0);

    // hand off to the deferred fold; read next tc from LDS (cheap ds_read)
    #pragma unroll
    for (int mi = 0; mi < 2; ++mi)
      #pragma unroll
      for (int ni = 0; ni < 4; ++ni)
        accP[mi][ni] = acc[mi][ni];
    #pragma unroll
    for (int ni = 0; ni < 4; ++ni) tcP[ni] = tgts[g*HBN + ni*16 + l15];

    __builtin_amdgcn_s_barrier();            // Bs[g&1] reads done before overwrite
  }

  // ---- final fold (step GT-1) ----
  #pragma unroll
  for (int mi = 0; mi < 2; ++mi)
    #pragma unroll
    for (int ni = 0; ni < 4; ++ni)
      #pragma unroll
      for (int r = 0; r < 4; ++r) {
        float v = accP[mi][ni][r];
        se[mi][r] += __builtin_amdgcn_exp2f(fmaf(v, C1, C0));
        if (tcP[ni] == trow[mi][r]) ms[mi][r] += v;
      }
  // subtract the g=-1 dummy fold of zeros: exp2(C0) added once per (mi,r) x 4 ni
  {
    float dummy = 16.0f * __builtin_amdgcn_exp2f(C0);   // 16 zero-elements folded
    #pragma unroll
    for (int mi = 0; mi < 2; ++mi)
      #pragma unroll
      for (int r = 0; r < 4; ++r) se[mi][r] -= dummy;
    // ms dummy: v=0 adds 0 regardless of the mask compare -> nothing to undo
  }

  // reduce across the 16 lanes of each quad (cols), write per-row partials
  #pragma unroll
  for (int mi = 0; mi < 2; ++mi)
    #pragma unroll
    for (int r = 0; r < 4; ++r) {
      float s = se[mi][r], m = ms[mi][r];
      #pragma unroll
      for (int off = 1; off < 16; off <<= 1) {
        s += __shfl_xor(s, off, 64);
        m += __shfl_xor(m, off, 64);
      }
      if (l15 == 0) {
        int row = rowbase + wave*32 + mi*16 + quad*4 + r;
        psum[(size_t)split * N + row]  = s;
        pmask[(size_t)split * N + row] = m;
      }
    }
}

// finalize: 32 blocks x 256 rows each; per-block histogram (targets L2-hot),
// per-row term, wave reduce, one atomicAdd per block into pre-zeroed out.
__global__ __launch_bounds__(256) void kfinal(
    const float* __restrict__ psum, const float* __restrict__ pmask,
    const int* __restrict__ tgt, float* __restrict__ out, int N) {
  __shared__ int h[128];
  __shared__ float wsum[4];
  const int tid = threadIdx.x;
  if (tid < 128) h[tid] = 0;
  __syncthreads();
  for (int i = tid; i < N; i += 256) atomicAdd(&h[tgt[i] & 127], 1);
  __syncthreads();

  const int i = blockIdx.x * 256 + tid;
  float s = 0.f, m = 0.f;
  #pragma unroll
  for (int sp = 0; sp < NSPLIT; ++sp) {
    s += psum[(size_t)sp * N + i];
    m += pmask[(size_t)sp * N + i];
  }
  const float invT = 1.0f / TEMP;
  float cnt = (float)(h[tgt[i] & 127] - 1);
  // LSE_i = invT + log(s);  sum_mask sim = (m - selfdot(~1.0)) * invT
  float term = (m - 1.0f) * invT / cnt - (logf(s) + invT);
  #pragma unroll
  for (int off = 1; off < 64; off <<= 1) term += __shfl_xor(term, off, 64);
  if ((tid & 63) == 0) wsum[tid >> 6] = term;
  __syncthreads();
  if (tid == 0)
    atomicAdd(out, -(wsum[0] + wsum[1] + wsum[2] + wsum[3]) / (float)N);
}

extern "C" void kernel_launch(void* const* d_in, const int* in_sizes, int n_in,
                              void* d_out, int out_size, void* d_ws, size_t ws_size,
                              hipStream_t stream) {
  const float* X  = (const float*)d_in[0];
  const int* tgt  = (const int*)d_in[1];
  float* out      = (float*)d_out;
  const int N = in_sizes[1];
  const int D = in_sizes[0] / N;

  char* w = (char*)d_ws;
  unsigned char* Fq = (unsigned char*)w;
  size_t off = (size_t)N * D;                          // fp8: 1 B/elem
  float* psum  = (float*)(w + off); off += (size_t)NSPLIT * N * sizeof(float);
  float* pmask = (float*)(w + off);

  knorm<<<N / 4, 256, 0, stream>>>(X, Fq, out, D);
  kmain<<<(N / BM) * NSPLIT, 256, 0, stream>>>(Fq, tgt, psum, pmask, N, D);
  kfinal<<<N / 256, 256, 0, stream>>>(psum, pmask, tgt, out, N);
}